// Round 4
// baseline (409.935 us; speedup 1.0000x reference)
//
#include <hip/hip_runtime.h>
#include <math.h>

// GATConv forward:
//   k_cast_w    : Wbf[n][k] = bf16(W[n][k])   (B^T layout for feat @ W.T)
//   k_gemm_mfma : barrier-free MFMA GEMM. One wave per 16 rows x 256 cols.
//                 A fp32->bf16 in-register from global (each byte read once);
//                 B 16B fragments straight from L2 (128 KB table, redundant
//                 reads ~800 MB @ 34.5 TB/s L2 = hidden). Fused el/er.
//                 C repacked via wave-private LDS -> coalesced 512B row writes.
//   k_aggregate : per-dst edge softmax (deg==16) + weighted bf16 gather-sum;
//                 nontemporal out stores to keep fs_bf resident in L2/L3.
//
// N=100000, IN=256, H=4, D=64, E=N*16; degree uniformly 16.

#define HEADS 4
#define KIN 256
#define NOUT 256
#define NEG_SLOPE 0.2f
#define SR 280  // repack LDS row stride in ushorts (560B: 16B-aligned rows,
                // row-pair bank shift 12 -> worst 4-way conflict on b16 writes)

typedef __attribute__((ext_vector_type(8))) short short8v;
typedef __attribute__((ext_vector_type(4))) float floatx4;

static __device__ __forceinline__ unsigned short f2bf(float x) {
  unsigned u = __float_as_uint(x);
  u += 0x7FFFu + ((u >> 16) & 1u);  // RNE; inputs are finite
  return (unsigned short)(u >> 16);
}
static __device__ __forceinline__ float bf2f(unsigned short b) {
  return __uint_as_float(((unsigned)b) << 16);
}

__global__ __launch_bounds__(256) void k_cast_w(const float* __restrict__ W,
                                                unsigned short* __restrict__ Wbf) {
  const int i = blockIdx.x * 256 + threadIdx.x;  // float4 index, 16384 total
  float4 f = ((const float4*)W)[i];
  ushort4 o;
  o.x = f2bf(f.x); o.y = f2bf(f.y); o.z = f2bf(f.z); o.w = f2bf(f.w);
  ((ushort4*)Wbf)[i] = o;
}

// Block = 256 = 4 waves; wave w owns rows [blk*64 + 16w, +16), cols 0..255.
// Per wave: 16 accumulator tiles (16x16), K in 8 chunks of 32.
// A-frag: lane l15 <-> row, quad q <-> k-octet. C/D: col=l15, row=q*4+r.
__global__ __launch_bounds__(256, 2) void k_gemm_mfma(
    const float* __restrict__ feat, const unsigned short* __restrict__ Wbf,
    const float* __restrict__ attn_l, const float* __restrict__ attn_r,
    unsigned short* __restrict__ fs_bf, float* __restrict__ el,
    float* __restrict__ er, int n_nodes) {
  __shared__ unsigned short R[4 * 16 * SR];  // 35840 B, wave-private slices

  const int tid = threadIdx.x;
  const int lane = tid & 63;
  const int w = tid >> 6;
  const int q = lane >> 4;
  const int l15 = lane & 15;
  const int m0 = blockIdx.x * 64 + w * 16;

  int arow_i = m0 + l15;
  if (arow_i >= n_nodes) arow_i = n_nodes - 1;  // tail clamp; stores guarded
  const float* __restrict__ arow = feat + (size_t)arow_i * KIN;

  floatx4 acc[16];
#pragma unroll
  for (int nt = 0; nt < 16; ++nt) acc[nt] = (floatx4)0.f;

#pragma unroll
  for (int kc = 0; kc < 8; ++kc) {
    const int k0 = kc * 32 + q * 8;
    float4 a0 = *(const float4*)(arow + k0);
    float4 a1 = *(const float4*)(arow + k0 + 4);
    short8v af;
    af[0] = f2bf(a0.x); af[1] = f2bf(a0.y); af[2] = f2bf(a0.z); af[3] = f2bf(a0.w);
    af[4] = f2bf(a1.x); af[5] = f2bf(a1.y); af[6] = f2bf(a1.z); af[7] = f2bf(a1.w);
#pragma unroll
    for (int nt = 0; nt < 16; ++nt) {
      short8v bf = *(const short8v*)(Wbf + (size_t)(nt * 16 + l15) * KIN + k0);
      acc[nt] = __builtin_amdgcn_mfma_f32_16x16x32_bf16(af, bf, acc[nt], 0, 0, 0);
    }
  }

  // ---- el/er: rows m0+q*4+r; head h covers tiles nt=4h..4h+3
  float al_[16], ar_[16];
#pragma unroll
  for (int nt = 0; nt < 16; ++nt) {
    al_[nt] = attn_l[nt * 16 + l15];
    ar_[nt] = attn_r[nt * 16 + l15];
  }
#pragma unroll
  for (int r = 0; r < 4; ++r) {
    const int m = m0 + q * 4 + r;
    float pl[HEADS], pr[HEADS];
#pragma unroll
    for (int h = 0; h < HEADS; ++h) {
      pl[h] = 0.f; pr[h] = 0.f;
#pragma unroll
      for (int t = 0; t < 4; ++t) {
        const int nt = h * 4 + t;
        const float v = acc[nt][r];
        pl[h] = fmaf(v, al_[nt], pl[h]);
        pr[h] = fmaf(v, ar_[nt], pr[h]);
      }
#pragma unroll
      for (int off = 1; off < 16; off <<= 1) {
        pl[h] += __shfl_xor(pl[h], off, 64);
        pr[h] += __shfl_xor(pr[h], off, 64);
      }
    }
    if (m < n_nodes && l15 < HEADS) {
      float vl = pl[0], vr = pr[0];
      if (l15 == 1) { vl = pl[1]; vr = pr[1]; }
      else if (l15 == 2) { vl = pl[2]; vr = pr[2]; }
      else if (l15 == 3) { vl = pl[3]; vr = pr[3]; }
      el[m * HEADS + l15] = vl;
      er[m * HEADS + l15] = vr;
    }
  }

  // ---- repack C through wave-private LDS, store coalesced 512B rows.
  // No __syncthreads needed: each wave touches only its own slice; the
  // compiler orders ds_write->ds_read via lgkmcnt.
  unsigned short* Rw = &R[w * 16 * SR];
#pragma unroll
  for (int nt = 0; nt < 16; ++nt)
#pragma unroll
    for (int r = 0; r < 4; ++r)
      Rw[(q * 4 + r) * SR + nt * 16 + l15] = f2bf(acc[nt][r]);

  const int rrow = lane >> 5;      // 0..1
  const int c8 = (lane & 31) * 8;  // ushort col, 16B per lane
#pragma unroll
  for (int t = 0; t < 8; ++t) {
    const int row = t * 2 + rrow;
    const int m = m0 + row;
    short8v v = *(const short8v*)(&Rw[row * SR + c8]);
    if (m < n_nodes)
      *(short8v*)(fs_bf + (size_t)m * NOUT + c8) = v;
  }
}

// One wave per dst node. Softmax: lane = h*16 + j. Accumulate: lane = ushort4
// chunk of the 256-col row (head = lane>>4 in both phases).
__global__ __launch_bounds__(256) void k_aggregate(
    const int* __restrict__ row_ptr, const int* __restrict__ col_ind,
    const float* __restrict__ el, const float* __restrict__ er,
    const unsigned short* __restrict__ fs_bf, float* __restrict__ out,
    int n_nodes) {
  const int gid = blockIdx.x * blockDim.x + threadIdx.x;
  const int node = gid >> 6;
  const int lane = threadIdx.x & 63;
  if (node >= n_nodes) return;

  const int h = lane >> 4;
  const int j = lane & 15;
  const int rs = row_ptr[node];
  const int deg = row_ptr[node + 1] - rs;  // == 16 by construction

  const bool valid = (j < deg);
  const int src = valid ? col_ind[rs + j] : 0;

  float e = valid ? (er[src * HEADS + h] + el[node * HEADS + h]) : -INFINITY;
  e = (e > 0.f) ? e : NEG_SLOPE * e;  // LeakyReLU

  float mx = e;
#pragma unroll
  for (int off = 1; off < 16; off <<= 1) mx = fmaxf(mx, __shfl_xor(mx, off, 64));
  float ex = valid ? __expf(e - mx) : 0.f;
  float s = ex;
#pragma unroll
  for (int off = 1; off < 16; off <<= 1) s += __shfl_xor(s, off, 64);
  const float a = ex / s;

  const ushort4* __restrict__ fs4 = (const ushort4*)fs_bf;
  const int hbase = lane & 48;
  floatx4 acc = (floatx4)0.f;
#pragma unroll
  for (int j2 = 0; j2 < 16; ++j2) {
    const int sj = __shfl(src, j2, 64);
    const float wgt = __shfl(a, hbase + j2, 64);
    const ushort4 u = fs4[(size_t)sj * (NOUT / 4) + lane];  // 512B/row coalesced
    acc.x = fmaf(wgt, bf2f(u.x), acc.x);
    acc.y = fmaf(wgt, bf2f(u.y), acc.y);
    acc.z = fmaf(wgt, bf2f(u.z), acc.z);
    acc.w = fmaf(wgt, bf2f(u.w), acc.w);
  }
  // out is write-once streaming: nontemporal keeps fs_bf resident in L2/L3.
  // (floatx4 is a native clang ext-vector — HIP float4 is rejected by the builtin)
  __builtin_nontemporal_store(acc, (floatx4*)out + (size_t)node * (NOUT / 4) + lane);
}

extern "C" void kernel_launch(void* const* d_in, const int* in_sizes, int n_in,
                              void* d_out, int out_size, void* d_ws, size_t ws_size,
                              hipStream_t stream) {
  const int* row_ptr = (const int*)d_in[0];
  const int* col_ind = (const int*)d_in[1];
  const float* feat = (const float*)d_in[2];
  const float* W = (const float*)d_in[3];
  const float* attn_l = (const float*)d_in[4];
  const float* attn_r = (const float*)d_in[5];
  float* out = (float*)d_out;
  const int n_nodes = in_sizes[0] - 1;

  // Workspace: Wbf (128 KB) | feat_src bf16 (51.2 MB) | el, er (1.6 MB each)
  char* ws = (char*)d_ws;
  unsigned short* Wbf = (unsigned short*)ws;
  unsigned short* fs_bf = (unsigned short*)(ws + 128 * 1024);
  size_t fs_bytes = (size_t)n_nodes * NOUT * sizeof(unsigned short);
  float* el = (float*)(ws + 128 * 1024 + fs_bytes);
  float* er = el + (size_t)n_nodes * HEADS;

  k_cast_w<<<64, 256, 0, stream>>>(W, Wbf);
  k_gemm_mfma<<<(n_nodes + 63) / 64, 256, 0, stream>>>(
      feat, Wbf, attn_l, attn_r, fs_bf, el, er, n_nodes);
  k_aggregate<<<(n_nodes + 3) / 4, 256, 0, stream>>>(
      row_ptr, col_ind, el, er, fs_bf, out, n_nodes);
}